// Round 2
// baseline (814.648 us; speedup 1.0000x reference)
//
#include <hip/hip_runtime.h>

#define NPTS 16384
#define NBATCH 256
constexpr int THREADS  = 256;                  // 4 waves per block
constexpr int EPT      = 4;                    // points per thread (float4)
constexpr int CHUNKPTS = THREADS * EPT;        // 1024 points per block
constexpr int NCH      = NPTS / CHUNKPTS;      // 16 chunks per batch row
constexpr int NBLK     = NBATCH * NCH;         // 4096 blocks
constexpr int NWAVES   = THREADS / 64;         // 4

struct Ws {
  unsigned int flags[NBLK];
  unsigned int counter;
  unsigned int pad[3];
  float vx[NBLK];
  float vy[NBLK];
  float vz[NBLK];
};

__device__ __forceinline__ float4 ld4(const float* p) {
  return *reinterpret_cast<const float4*>(p);
}

__global__ __launch_bounds__(THREADS) void mpd_loss_kernel(
    const float* __restrict__ o3, const float* __restrict__ s3,
    const float* __restrict__ o2, const float* __restrict__ s2,
    const float* __restrict__ df, float* __restrict__ out, Ws* __restrict__ ws) {
  const int t = threadIdx.x;
  const int lane = t & 63;
  const int wave = t >> 6;

  __shared__ unsigned int ticket_s;
  __shared__ float wtot[3][NWAVES];
  __shared__ float carry_s[3];
  __shared__ float redbuf[NWAVES];

  // execution-order virtual block id -> no deadlock on the carry chain
  if (t == 0) ticket_s = atomicAdd(&ws->counter, 1u);
  __syncthreads();
  const int vb = (int)ticket_s;
  const int b = vb >> 4;       // batch row
  const int c = vb & (NCH - 1);// chunk within row

  const float* r3p = s3 + (size_t)b * 3 * NPTS;
  const float* t3p = r3p + NPTS;
  const float* p3p = r3p + 2 * NPTS;
  const float* r2p = s2 + (size_t)b * 3 * NPTS;
  const float* t2p = r2p + NPTS;
  const float* p2p = r2p + 2 * NPTS;
  const float* dtp = df + (size_t)b * 2 * NPTS;
  const float* dpp = dtp + NPTS;

  const int idx = c * CHUNKPTS + t * EPT;
  float4 cR3 = ld4(r3p + idx), cT3 = ld4(t3p + idx), cP3 = ld4(p3p + idx);
  float4 cR2 = ld4(r2p + idx), cT2 = ld4(t2p + idx), cP2 = ld4(p2p + idx);
  float4 cDT = ld4(dtp + idx), cDP = ld4(dpp + idx);

  const float* fR3 = reinterpret_cast<const float*>(&cR3);
  const float* fT3 = reinterpret_cast<const float*>(&cT3);
  const float* fP3 = reinterpret_cast<const float*>(&cP3);
  const float* fR2 = reinterpret_cast<const float*>(&cR2);
  const float* fT2 = reinterpret_cast<const float*>(&cT2);
  const float* fP2 = reinterpret_cast<const float*>(&cP2);
  const float* fDT = reinterpret_cast<const float*>(&cDT);
  const float* fDP = reinterpret_cast<const float*>(&cDP);

  // per-point difference d = shape3 - shape2, thread-local inclusive prefix
  float px[EPT], py[EPT], pz[EPT];
  float sx = 0.f, sy = 0.f, sz = 0.f;
  #pragma unroll
  for (int e = 0; e < EPT; ++e) {
    float r3v = fR3[e];
    float th3 = fT3[e] + fDT[e];
    float ph3 = fP3[e] + fDP[e];
    float r2v = fR2[e];
    float th2 = fT2[e];
    float ph2 = fP2[e];
    float st3 = __sinf(th3), ct3 = __cosf(th3);
    float sp3 = __sinf(ph3), cp3 = __cosf(ph3);
    float st2 = __sinf(th2), ct2 = __cosf(th2);
    float sp2 = __sinf(ph2), cp2 = __cosf(ph2);
    sx += r3v * st3 * cp3 - r2v * st2 * cp2; px[e] = sx;
    sy += r3v * st3 * sp3 - r2v * st2 * sp2; py[e] = sy;
    sz += r3v * ct3 - r2v * ct2;             pz[e] = sz;
  }

  // wave-level inclusive scan of thread totals
  float ix = sx, iy = sy, iz = sz;
  #pragma unroll
  for (int off = 1; off < 64; off <<= 1) {
    float ax = __shfl_up(ix, off, 64);
    float ay = __shfl_up(iy, off, 64);
    float az = __shfl_up(iz, off, 64);
    if (lane >= off) { ix += ax; iy += ay; iz += az; }
  }
  const float exs = ix - sx, eys = iy - sy, ezs = iz - sz;

  if (lane == 63) { wtot[0][wave] = ix; wtot[1][wave] = iy; wtot[2][wave] = iz; }
  __syncthreads();

  float wx = 0.f, wy = 0.f, wz = 0.f;   // offset of previous waves
  float agx = 0.f, agy = 0.f, agz = 0.f;// block aggregate
  #pragma unroll
  for (int w = 0; w < NWAVES; ++w) {
    float vx = wtot[0][w], vy = wtot[1][w], vz = wtot[2][w];
    if (w < wave) { wx += vx; wy += vy; wz += vz; }
    agx += vx; agy += vy; agz += vz;
  }

  // chained carry: wait for V_{c-1}, publish V_c = V_{c-1} + aggregate
  if (t == 0) {
    float Vx = 0.f, Vy = 0.f, Vz = 0.f;
    if (c > 0) {
      const int pr = vb - 1;
      while (__hip_atomic_load(&ws->flags[pr], __ATOMIC_ACQUIRE,
                               __HIP_MEMORY_SCOPE_AGENT) == 0u) {
        __builtin_amdgcn_s_sleep(1);
      }
      Vx = __hip_atomic_load(&ws->vx[pr], __ATOMIC_RELAXED, __HIP_MEMORY_SCOPE_AGENT);
      Vy = __hip_atomic_load(&ws->vy[pr], __ATOMIC_RELAXED, __HIP_MEMORY_SCOPE_AGENT);
      Vz = __hip_atomic_load(&ws->vz[pr], __ATOMIC_RELAXED, __HIP_MEMORY_SCOPE_AGENT);
    }
    __hip_atomic_store(&ws->vx[vb], Vx + agx, __ATOMIC_RELAXED, __HIP_MEMORY_SCOPE_AGENT);
    __hip_atomic_store(&ws->vy[vb], Vy + agy, __ATOMIC_RELAXED, __HIP_MEMORY_SCOPE_AGENT);
    __hip_atomic_store(&ws->vz[vb], Vz + agz, __ATOMIC_RELAXED, __HIP_MEMORY_SCOPE_AGENT);
    __hip_atomic_store(&ws->flags[vb], 1u, __ATOMIC_RELEASE, __HIP_MEMORY_SCOPE_AGENT);
    // carry for this chunk = origin diff + V_{c-1}
    carry_s[0] = (o3[b * 3 + 0] - o2[b * 3 + 0]) + Vx;
    carry_s[1] = (o3[b * 3 + 1] - o2[b * 3 + 1]) + Vy;
    carry_s[2] = (o3[b * 3 + 2] - o2[b * 3 + 2]) + Vz;
  }
  __syncthreads();

  const float bx = carry_s[0] + wx + exs;
  const float by = carry_s[1] + wy + eys;
  const float bz = carry_s[2] + wz + ezs;

  float acc = 0.f;
  #pragma unroll
  for (int e = 0; e < EPT; ++e) {
    acc += fabsf(bx + px[e]) + fabsf(by + py[e]) + fabsf(bz + pz[e]);
  }
  // j=0 element of the cumsum (the origin itself)
  if (c == 0 && t == 0) {
    acc += fabsf(o3[b * 3 + 0] - o2[b * 3 + 0]) +
           fabsf(o3[b * 3 + 1] - o2[b * 3 + 1]) +
           fabsf(o3[b * 3 + 2] - o2[b * 3 + 2]);
  }

  #pragma unroll
  for (int off = 32; off > 0; off >>= 1) acc += __shfl_down(acc, off, 64);
  if (lane == 0) redbuf[wave] = acc;
  __syncthreads();
  if (t == 0) {
    float s = 0.f;
    #pragma unroll
    for (int w = 0; w < NWAVES; ++w) s += redbuf[w];
    atomicAdd(out, s * (1.0f / (float)(NPTS + 1)));
  }
}

extern "C" void kernel_launch(void* const* d_in, const int* in_sizes, int n_in,
                              void* d_out, int out_size, void* d_ws, size_t ws_size,
                              hipStream_t stream) {
  const float* o3 = (const float*)d_in[0];  // origin_3D      (B,3,1)
  const float* s3 = (const float*)d_in[1];  // spherical_3D   (B,3,N)
  const float* o2 = (const float*)d_in[2];  // origin_2D      (B,3,1)
  const float* s2 = (const float*)d_in[3];  // spherical_2D   (B,3,N)
  const float* df = (const float*)d_in[4];  // deformation    (B,2,N)
  float* out = (float*)d_out;
  Ws* ws = (Ws*)d_ws;

  // flags + ticket counter must be zero at every (replayed) launch;
  // d_out accumulates via atomicAdd so it must be zeroed too.
  hipMemsetAsync(ws, 0, sizeof(unsigned int) * (NBLK + 4), stream);
  hipMemsetAsync(out, 0, sizeof(float) * out_size, stream);
  mpd_loss_kernel<<<NBLK, THREADS, 0, stream>>>(o3, s3, o2, s2, df, out, ws);
}

// Round 3
// 89.410 us; speedup vs baseline: 9.1114x; 9.1114x over previous
//
#include <hip/hip_runtime.h>

#define NPTS 16384
#define NBATCH 256
constexpr int THREADS  = 256;                  // 4 waves per block
constexpr int EPT      = 4;                    // points per thread (float4)
constexpr int CHUNKPTS = THREADS * EPT;        // 1024 points per block
constexpr int NCH      = NPTS / CHUNKPTS;      // 16 chunks per batch row
constexpr int NBLK     = NBATCH * NCH;         // 4096 blocks
constexpr int NWAVES   = THREADS / 64;         // 4

__device__ __forceinline__ float4 ld4(const float* p) {
  return *reinterpret_cast<const float4*>(p);
}

// ---------------- Kernel 1: per-chunk diff aggregates ----------------
__global__ __launch_bounds__(THREADS) void k_agg(
    const float* __restrict__ s3, const float* __restrict__ s2,
    const float* __restrict__ df, float4* __restrict__ agg) {
  const int blk = blockIdx.x;
  const int b = blk >> 4;
  const int c = blk & (NCH - 1);
  const int t = threadIdx.x;
  const int lane = t & 63;
  const int wave = t >> 6;

  const float* r3p = s3 + (size_t)b * 3 * NPTS;
  const float* t3p = r3p + NPTS;
  const float* p3p = r3p + 2 * NPTS;
  const float* r2p = s2 + (size_t)b * 3 * NPTS;
  const float* t2p = r2p + NPTS;
  const float* p2p = r2p + 2 * NPTS;
  const float* dtp = df + (size_t)b * 2 * NPTS;
  const float* dpp = dtp + NPTS;

  const int idx = c * CHUNKPTS + t * EPT;
  float4 cR3 = ld4(r3p + idx), cT3 = ld4(t3p + idx), cP3 = ld4(p3p + idx);
  float4 cR2 = ld4(r2p + idx), cT2 = ld4(t2p + idx), cP2 = ld4(p2p + idx);
  float4 cDT = ld4(dtp + idx), cDP = ld4(dpp + idx);

  const float* fR3 = reinterpret_cast<const float*>(&cR3);
  const float* fT3 = reinterpret_cast<const float*>(&cT3);
  const float* fP3 = reinterpret_cast<const float*>(&cP3);
  const float* fR2 = reinterpret_cast<const float*>(&cR2);
  const float* fT2 = reinterpret_cast<const float*>(&cT2);
  const float* fP2 = reinterpret_cast<const float*>(&cP2);
  const float* fDT = reinterpret_cast<const float*>(&cDT);
  const float* fDP = reinterpret_cast<const float*>(&cDP);

  float sx = 0.f, sy = 0.f, sz = 0.f;
  #pragma unroll
  for (int e = 0; e < EPT; ++e) {
    float r3v = fR3[e];
    float th3 = fT3[e] + fDT[e];
    float ph3 = fP3[e] + fDP[e];
    float r2v = fR2[e];
    float th2 = fT2[e];
    float ph2 = fP2[e];
    float st3 = __sinf(th3), ct3 = __cosf(th3);
    float sp3 = __sinf(ph3), cp3 = __cosf(ph3);
    float st2 = __sinf(th2), ct2 = __cosf(th2);
    float sp2 = __sinf(ph2), cp2 = __cosf(ph2);
    sx += r3v * st3 * cp3 - r2v * st2 * cp2;
    sy += r3v * st3 * sp3 - r2v * st2 * sp2;
    sz += r3v * ct3 - r2v * ct2;
  }

  // wave reduce
  #pragma unroll
  for (int off = 32; off > 0; off >>= 1) {
    sx += __shfl_down(sx, off, 64);
    sy += __shfl_down(sy, off, 64);
    sz += __shfl_down(sz, off, 64);
  }
  __shared__ float wtot[3][NWAVES];
  if (lane == 0) { wtot[0][wave] = sx; wtot[1][wave] = sy; wtot[2][wave] = sz; }
  __syncthreads();
  if (t == 0) {
    float ax = 0.f, ay = 0.f, az = 0.f;
    #pragma unroll
    for (int w = 0; w < NWAVES; ++w) { ax += wtot[0][w]; ay += wtot[1][w]; az += wtot[2][w]; }
    agg[blk] = make_float4(ax, ay, az, 0.f);
  }
}

// ---------------- Kernel 2: scan + abs-reduce (re-reads inputs, L3-hot) ----
__global__ __launch_bounds__(THREADS) void k_scan(
    const float* __restrict__ o3, const float* __restrict__ s3,
    const float* __restrict__ o2, const float* __restrict__ s2,
    const float* __restrict__ df, const float4* __restrict__ agg,
    float* __restrict__ out) {
  const int blk = blockIdx.x;
  const int b = blk >> 4;
  const int c = blk & (NCH - 1);
  const int t = threadIdx.x;
  const int lane = t & 63;
  const int wave = t >> 6;

  const float* r3p = s3 + (size_t)b * 3 * NPTS;
  const float* t3p = r3p + NPTS;
  const float* p3p = r3p + 2 * NPTS;
  const float* r2p = s2 + (size_t)b * 3 * NPTS;
  const float* t2p = r2p + NPTS;
  const float* p2p = r2p + 2 * NPTS;
  const float* dtp = df + (size_t)b * 2 * NPTS;
  const float* dpp = dtp + NPTS;

  const int idx = c * CHUNKPTS + t * EPT;
  float4 cR3 = ld4(r3p + idx), cT3 = ld4(t3p + idx), cP3 = ld4(p3p + idx);
  float4 cR2 = ld4(r2p + idx), cT2 = ld4(t2p + idx), cP2 = ld4(p2p + idx);
  float4 cDT = ld4(dtp + idx), cDP = ld4(dpp + idx);

  // carry for this chunk: origin diff + sum of preceding chunk aggregates
  // (uniform across the block; <=15 L2-hot float4 loads)
  const float ox = o3[b * 3 + 0] - o2[b * 3 + 0];
  const float oy = o3[b * 3 + 1] - o2[b * 3 + 1];
  const float oz = o3[b * 3 + 2] - o2[b * 3 + 2];
  float carx = ox, cary = oy, carz = oz;
  for (int cc = 0; cc < c; ++cc) {
    float4 a = agg[(b << 4) + cc];
    carx += a.x; cary += a.y; carz += a.z;
  }

  const float* fR3 = reinterpret_cast<const float*>(&cR3);
  const float* fT3 = reinterpret_cast<const float*>(&cT3);
  const float* fP3 = reinterpret_cast<const float*>(&cP3);
  const float* fR2 = reinterpret_cast<const float*>(&cR2);
  const float* fT2 = reinterpret_cast<const float*>(&cT2);
  const float* fP2 = reinterpret_cast<const float*>(&cP2);
  const float* fDT = reinterpret_cast<const float*>(&cDT);
  const float* fDP = reinterpret_cast<const float*>(&cDP);

  float px[EPT], py[EPT], pz[EPT];
  float sx = 0.f, sy = 0.f, sz = 0.f;
  #pragma unroll
  for (int e = 0; e < EPT; ++e) {
    float r3v = fR3[e];
    float th3 = fT3[e] + fDT[e];
    float ph3 = fP3[e] + fDP[e];
    float r2v = fR2[e];
    float th2 = fT2[e];
    float ph2 = fP2[e];
    float st3 = __sinf(th3), ct3 = __cosf(th3);
    float sp3 = __sinf(ph3), cp3 = __cosf(ph3);
    float st2 = __sinf(th2), ct2 = __cosf(th2);
    float sp2 = __sinf(ph2), cp2 = __cosf(ph2);
    sx += r3v * st3 * cp3 - r2v * st2 * cp2; px[e] = sx;
    sy += r3v * st3 * sp3 - r2v * st2 * sp2; py[e] = sy;
    sz += r3v * ct3 - r2v * ct2;             pz[e] = sz;
  }

  // wave-level inclusive scan of thread totals
  float ix = sx, iy = sy, iz = sz;
  #pragma unroll
  for (int off = 1; off < 64; off <<= 1) {
    float ax = __shfl_up(ix, off, 64);
    float ay = __shfl_up(iy, off, 64);
    float az = __shfl_up(iz, off, 64);
    if (lane >= off) { ix += ax; iy += ay; iz += az; }
  }
  const float exs = ix - sx, eys = iy - sy, ezs = iz - sz;

  __shared__ float wtot[3][NWAVES];
  __shared__ float redbuf[NWAVES];
  if (lane == 63) { wtot[0][wave] = ix; wtot[1][wave] = iy; wtot[2][wave] = iz; }
  __syncthreads();

  float wx = 0.f, wy = 0.f, wz = 0.f;   // offset of previous waves
  #pragma unroll
  for (int w = 0; w < NWAVES; ++w) {
    float vx = wtot[0][w], vy = wtot[1][w], vz = wtot[2][w];
    if (w < wave) { wx += vx; wy += vy; wz += vz; }
  }

  const float bx = carx + wx + exs;
  const float by = cary + wy + eys;
  const float bz = carz + wz + ezs;

  float acc = 0.f;
  #pragma unroll
  for (int e = 0; e < EPT; ++e) {
    acc += fabsf(bx + px[e]) + fabsf(by + py[e]) + fabsf(bz + pz[e]);
  }
  // j=0 element of the cumsum (the origin itself), once per row
  if (c == 0 && t == 0) {
    acc += fabsf(ox) + fabsf(oy) + fabsf(oz);
  }

  #pragma unroll
  for (int off = 32; off > 0; off >>= 1) acc += __shfl_down(acc, off, 64);
  if (lane == 0) redbuf[wave] = acc;
  __syncthreads();
  if (t == 0) {
    float s = 0.f;
    #pragma unroll
    for (int w = 0; w < NWAVES; ++w) s += redbuf[w];
    atomicAdd(out, s * (1.0f / (float)(NPTS + 1)));
  }
}

extern "C" void kernel_launch(void* const* d_in, const int* in_sizes, int n_in,
                              void* d_out, int out_size, void* d_ws, size_t ws_size,
                              hipStream_t stream) {
  const float* o3 = (const float*)d_in[0];  // origin_3D      (B,3,1)
  const float* s3 = (const float*)d_in[1];  // spherical_3D   (B,3,N)
  const float* o2 = (const float*)d_in[2];  // origin_2D      (B,3,1)
  const float* s2 = (const float*)d_in[3];  // spherical_2D   (B,3,N)
  const float* df = (const float*)d_in[4];  // deformation    (B,2,N)
  float* out = (float*)d_out;
  float4* agg = (float4*)d_ws;              // NBLK float4 = 64 KB

  // out accumulates via atomicAdd; harness doesn't re-zero between replays.
  hipMemsetAsync(out, 0, sizeof(float) * out_size, stream);
  k_agg<<<NBLK, THREADS, 0, stream>>>(s3, s2, df, agg);
  k_scan<<<NBLK, THREADS, 0, stream>>>(o3, s3, o2, s2, df, agg, out);
}

// Round 5
// 43.445 us; speedup vs baseline: 18.7511x; 2.0580x over previous
//
#include <hip/hip_runtime.h>

#define NPTS 16384
#define NBATCH 256

__device__ __forceinline__ float4 ld4(const float* p) {
  return *reinterpret_cast<const float4*>(p);
}

// ======================= Pipeline A: diff-store (needs ~50 MB ws) =========
constexpr int A_THREADS = 256;               // 4 waves
constexpr int A_EPT     = 8;                 // 8 points per thread
constexpr int A_CHUNK   = A_THREADS * A_EPT; // 2048 points per block
constexpr int A_NCH     = NPTS / A_CHUNK;    // 8 chunks per row
constexpr int A_NBLK    = NBATCH * A_NCH;    // 2048 blocks
constexpr int A_NW      = A_THREADS / 64;    // 4
constexpr size_t NPOINTS = (size_t)NBATCH * NPTS;          // 4,194,304
constexpr size_t WS_AGG_OFF     = 0;                        // float4[A_NBLK] = 32 KB
constexpr size_t WS_PARTIAL_OFF = 32 * 1024;                // float[A_NBLK] = 8 KB
constexpr size_t WS_DX_OFF      = 64 * 1024;
constexpr size_t WS_NEED = WS_DX_OFF + 3 * NPOINTS * sizeof(float);

// K1: read inputs once, store per-point diffs + per-chunk aggregates.
__global__ __launch_bounds__(A_THREADS) void k1_diff(
    const float* __restrict__ s3, const float* __restrict__ s2,
    const float* __restrict__ df, float4* __restrict__ agg,
    float* __restrict__ dx, float* __restrict__ dy, float* __restrict__ dz) {
  const int blk = blockIdx.x;
  const int b = blk >> 3;
  const int c = blk & (A_NCH - 1);
  const int t = threadIdx.x;
  const int lane = t & 63;
  const int wave = t >> 6;

  const float* r3p = s3 + (size_t)b * 3 * NPTS;
  const float* t3p = r3p + NPTS;
  const float* p3p = r3p + 2 * NPTS;
  const float* r2p = s2 + (size_t)b * 3 * NPTS;
  const float* t2p = r2p + NPTS;
  const float* p2p = r2p + 2 * NPTS;
  const float* dtp = df + (size_t)b * 2 * NPTS;
  const float* dpp = dtp + NPTS;

  const int idx = c * A_CHUNK + t * A_EPT;          // within-row point index
  const size_t gidx = (size_t)b * NPTS + idx;       // global point index (BUG FIX)

  float4 R3[2], T3[2], P3[2], R2[2], T2[2], P2[2], DT[2], DP[2];
  #pragma unroll
  for (int g = 0; g < 2; ++g) {
    R3[g] = ld4(r3p + idx + 4 * g);
    T3[g] = ld4(t3p + idx + 4 * g);
    P3[g] = ld4(p3p + idx + 4 * g);
    R2[g] = ld4(r2p + idx + 4 * g);
    T2[g] = ld4(t2p + idx + 4 * g);
    P2[g] = ld4(p2p + idx + 4 * g);
    DT[g] = ld4(dtp + idx + 4 * g);
    DP[g] = ld4(dpp + idx + 4 * g);
  }

  float dxv[A_EPT], dyv[A_EPT], dzv[A_EPT];
  float sx = 0.f, sy = 0.f, sz = 0.f;
  #pragma unroll
  for (int e = 0; e < A_EPT; ++e) {
    const int g = e >> 2, k = e & 3;
    float r3v = ((const float*)&R3[g])[k];
    float th3 = ((const float*)&T3[g])[k] + ((const float*)&DT[g])[k];
    float ph3 = ((const float*)&P3[g])[k] + ((const float*)&DP[g])[k];
    float r2v = ((const float*)&R2[g])[k];
    float th2 = ((const float*)&T2[g])[k];
    float ph2 = ((const float*)&P2[g])[k];
    float st3 = __sinf(th3), ct3 = __cosf(th3);
    float sp3 = __sinf(ph3), cp3 = __cosf(ph3);
    float st2 = __sinf(th2), ct2 = __cosf(th2);
    float sp2 = __sinf(ph2), cp2 = __cosf(ph2);
    dxv[e] = r3v * st3 * cp3 - r2v * st2 * cp2;
    dyv[e] = r3v * st3 * sp3 - r2v * st2 * sp2;
    dzv[e] = r3v * ct3 - r2v * ct2;
    sx += dxv[e]; sy += dyv[e]; sz += dzv[e];
  }

  *reinterpret_cast<float4*>(dx + gidx)     = make_float4(dxv[0], dxv[1], dxv[2], dxv[3]);
  *reinterpret_cast<float4*>(dx + gidx + 4) = make_float4(dxv[4], dxv[5], dxv[6], dxv[7]);
  *reinterpret_cast<float4*>(dy + gidx)     = make_float4(dyv[0], dyv[1], dyv[2], dyv[3]);
  *reinterpret_cast<float4*>(dy + gidx + 4) = make_float4(dyv[4], dyv[5], dyv[6], dyv[7]);
  *reinterpret_cast<float4*>(dz + gidx)     = make_float4(dzv[0], dzv[1], dzv[2], dzv[3]);
  *reinterpret_cast<float4*>(dz + gidx + 4) = make_float4(dzv[4], dzv[5], dzv[6], dzv[7]);

  #pragma unroll
  for (int off = 32; off > 0; off >>= 1) {
    sx += __shfl_down(sx, off, 64);
    sy += __shfl_down(sy, off, 64);
    sz += __shfl_down(sz, off, 64);
  }
  __shared__ float wtot[3][A_NW];
  if (lane == 0) { wtot[0][wave] = sx; wtot[1][wave] = sy; wtot[2][wave] = sz; }
  __syncthreads();
  if (t == 0) {
    float ax = 0.f, ay = 0.f, az = 0.f;
    #pragma unroll
    for (int w = 0; w < A_NW; ++w) { ax += wtot[0][w]; ay += wtot[1][w]; az += wtot[2][w]; }
    agg[blk] = make_float4(ax, ay, az, 0.f);
  }
}

// K2: scan the stored diffs (L3-hot), plain-store per-block partial sums.
__global__ __launch_bounds__(A_THREADS) void k2_scan(
    const float* __restrict__ o3, const float* __restrict__ o2,
    const float4* __restrict__ agg, const float* __restrict__ dx,
    const float* __restrict__ dy, const float* __restrict__ dz,
    float* __restrict__ partial) {
  const int blk = blockIdx.x;
  const int b = blk >> 3;
  const int c = blk & (A_NCH - 1);
  const int t = threadIdx.x;
  const int lane = t & 63;
  const int wave = t >> 6;

  const int idx = c * A_CHUNK + t * A_EPT;
  const size_t gidx = (size_t)b * NPTS + idx;       // global point index (BUG FIX)

  float4 DX[2], DY[2], DZ[2];
  #pragma unroll
  for (int g = 0; g < 2; ++g) {
    DX[g] = ld4(dx + gidx + 4 * g);
    DY[g] = ld4(dy + gidx + 4 * g);
    DZ[g] = ld4(dz + gidx + 4 * g);
  }

  // carry = origin diff + preceding chunk aggregates (uniform, L2-hot)
  const float ox = o3[b * 3 + 0] - o2[b * 3 + 0];
  const float oy = o3[b * 3 + 1] - o2[b * 3 + 1];
  const float oz = o3[b * 3 + 2] - o2[b * 3 + 2];
  float carx = ox, cary = oy, carz = oz;
  for (int cc = 0; cc < c; ++cc) {
    float4 a = agg[(b << 3) + cc];
    carx += a.x; cary += a.y; carz += a.z;
  }

  float px[A_EPT], py[A_EPT], pz[A_EPT];
  float sx = 0.f, sy = 0.f, sz = 0.f;
  #pragma unroll
  for (int e = 0; e < A_EPT; ++e) {
    const int g = e >> 2, k = e & 3;
    sx += ((const float*)&DX[g])[k]; px[e] = sx;
    sy += ((const float*)&DY[g])[k]; py[e] = sy;
    sz += ((const float*)&DZ[g])[k]; pz[e] = sz;
  }

  // wave-level inclusive scan of thread totals
  float ix = sx, iy = sy, iz = sz;
  #pragma unroll
  for (int off = 1; off < 64; off <<= 1) {
    float ax = __shfl_up(ix, off, 64);
    float ay = __shfl_up(iy, off, 64);
    float az = __shfl_up(iz, off, 64);
    if (lane >= off) { ix += ax; iy += ay; iz += az; }
  }
  const float exs = ix - sx, eys = iy - sy, ezs = iz - sz;

  __shared__ float wtot[3][A_NW];
  __shared__ float redbuf[A_NW];
  if (lane == 63) { wtot[0][wave] = ix; wtot[1][wave] = iy; wtot[2][wave] = iz; }
  __syncthreads();

  float wx = 0.f, wy = 0.f, wz = 0.f;
  #pragma unroll
  for (int w = 0; w < A_NW; ++w) {
    if (w < wave) { wx += wtot[0][w]; wy += wtot[1][w]; wz += wtot[2][w]; }
  }

  const float bx = carx + wx + exs;
  const float by = cary + wy + eys;
  const float bz = carz + wz + ezs;

  float acc = 0.f;
  #pragma unroll
  for (int e = 0; e < A_EPT; ++e) {
    acc += fabsf(bx + px[e]) + fabsf(by + py[e]) + fabsf(bz + pz[e]);
  }
  if (c == 0 && t == 0) acc += fabsf(ox) + fabsf(oy) + fabsf(oz);  // j=0 term

  #pragma unroll
  for (int off = 32; off > 0; off >>= 1) acc += __shfl_down(acc, off, 64);
  if (lane == 0) redbuf[wave] = acc;
  __syncthreads();
  if (t == 0) {
    float s = 0.f;
    #pragma unroll
    for (int w = 0; w < A_NW; ++w) s += redbuf[w];
    partial[blk] = s;
  }
}

// K3: reduce 2048 partials, write the loss (plain store, no memset needed).
__global__ __launch_bounds__(256) void k3_final(const float* __restrict__ partial,
                                                float* __restrict__ out) {
  const int t = threadIdx.x;
  const int lane = t & 63;
  const int wave = t >> 6;
  float s = 0.f;
  #pragma unroll
  for (int i = 0; i < A_NBLK / 256; ++i) s += partial[i * 256 + t];
  #pragma unroll
  for (int off = 32; off > 0; off >>= 1) s += __shfl_down(s, off, 64);
  __shared__ float red[4];
  if (lane == 0) red[wave] = s;
  __syncthreads();
  if (t == 0) {
    float tot = red[0] + red[1] + red[2] + red[3];
    out[0] = tot * (1.0f / (float)(NPTS + 1));
  }
}

// ======================= Pipeline B: fallback (round-3, ws < 50 MB) =======
constexpr int THREADS  = 256;
constexpr int EPT      = 4;
constexpr int CHUNKPTS = THREADS * EPT;        // 1024
constexpr int NCH      = NPTS / CHUNKPTS;      // 16
constexpr int NBLK     = NBATCH * NCH;         // 4096
constexpr int NWAVES   = THREADS / 64;         // 4

__global__ __launch_bounds__(THREADS) void k_agg(
    const float* __restrict__ s3, const float* __restrict__ s2,
    const float* __restrict__ df, float4* __restrict__ agg) {
  const int blk = blockIdx.x;
  const int b = blk >> 4;
  const int c = blk & (NCH - 1);
  const int t = threadIdx.x;
  const int lane = t & 63;
  const int wave = t >> 6;

  const float* r3p = s3 + (size_t)b * 3 * NPTS;
  const float* t3p = r3p + NPTS;
  const float* p3p = r3p + 2 * NPTS;
  const float* r2p = s2 + (size_t)b * 3 * NPTS;
  const float* t2p = r2p + NPTS;
  const float* p2p = r2p + 2 * NPTS;
  const float* dtp = df + (size_t)b * 2 * NPTS;
  const float* dpp = dtp + NPTS;

  const int idx = c * CHUNKPTS + t * EPT;
  float4 cR3 = ld4(r3p + idx), cT3 = ld4(t3p + idx), cP3 = ld4(p3p + idx);
  float4 cR2 = ld4(r2p + idx), cT2 = ld4(t2p + idx), cP2 = ld4(p2p + idx);
  float4 cDT = ld4(dtp + idx), cDP = ld4(dpp + idx);

  const float* fR3 = (const float*)&cR3; const float* fT3 = (const float*)&cT3;
  const float* fP3 = (const float*)&cP3; const float* fR2 = (const float*)&cR2;
  const float* fT2 = (const float*)&cT2; const float* fP2 = (const float*)&cP2;
  const float* fDT = (const float*)&cDT; const float* fDP = (const float*)&cDP;

  float sx = 0.f, sy = 0.f, sz = 0.f;
  #pragma unroll
  for (int e = 0; e < EPT; ++e) {
    float r3v = fR3[e];
    float th3 = fT3[e] + fDT[e];
    float ph3 = fP3[e] + fDP[e];
    float r2v = fR2[e];
    float th2 = fT2[e];
    float ph2 = fP2[e];
    float st3 = __sinf(th3), ct3 = __cosf(th3);
    float sp3 = __sinf(ph3), cp3 = __cosf(ph3);
    float st2 = __sinf(th2), ct2 = __cosf(th2);
    float sp2 = __sinf(ph2), cp2 = __cosf(ph2);
    sx += r3v * st3 * cp3 - r2v * st2 * cp2;
    sy += r3v * st3 * sp3 - r2v * st2 * sp2;
    sz += r3v * ct3 - r2v * ct2;
  }
  #pragma unroll
  for (int off = 32; off > 0; off >>= 1) {
    sx += __shfl_down(sx, off, 64);
    sy += __shfl_down(sy, off, 64);
    sz += __shfl_down(sz, off, 64);
  }
  __shared__ float wtot[3][NWAVES];
  if (lane == 0) { wtot[0][wave] = sx; wtot[1][wave] = sy; wtot[2][wave] = sz; }
  __syncthreads();
  if (t == 0) {
    float ax = 0.f, ay = 0.f, az = 0.f;
    #pragma unroll
    for (int w = 0; w < NWAVES; ++w) { ax += wtot[0][w]; ay += wtot[1][w]; az += wtot[2][w]; }
    agg[blk] = make_float4(ax, ay, az, 0.f);
  }
}

__global__ __launch_bounds__(THREADS) void k_scan(
    const float* __restrict__ o3, const float* __restrict__ s3,
    const float* __restrict__ o2, const float* __restrict__ s2,
    const float* __restrict__ df, const float4* __restrict__ agg,
    float* __restrict__ out) {
  const int blk = blockIdx.x;
  const int b = blk >> 4;
  const int c = blk & (NCH - 1);
  const int t = threadIdx.x;
  const int lane = t & 63;
  const int wave = t >> 6;

  const float* r3p = s3 + (size_t)b * 3 * NPTS;
  const float* t3p = r3p + NPTS;
  const float* p3p = r3p + 2 * NPTS;
  const float* r2p = s2 + (size_t)b * 3 * NPTS;
  const float* t2p = r2p + NPTS;
  const float* p2p = r2p + 2 * NPTS;
  const float* dtp = df + (size_t)b * 2 * NPTS;
  const float* dpp = dtp + NPTS;

  const int idx = c * CHUNKPTS + t * EPT;
  float4 cR3 = ld4(r3p + idx), cT3 = ld4(t3p + idx), cP3 = ld4(p3p + idx);
  float4 cR2 = ld4(r2p + idx), cT2 = ld4(t2p + idx), cP2 = ld4(p2p + idx);
  float4 cDT = ld4(dtp + idx), cDP = ld4(dpp + idx);

  const float ox = o3[b * 3 + 0] - o2[b * 3 + 0];
  const float oy = o3[b * 3 + 1] - o2[b * 3 + 1];
  const float oz = o3[b * 3 + 2] - o2[b * 3 + 2];
  float carx = ox, cary = oy, carz = oz;
  for (int cc = 0; cc < c; ++cc) {
    float4 a = agg[(b << 4) + cc];
    carx += a.x; cary += a.y; carz += a.z;
  }

  const float* fR3 = (const float*)&cR3; const float* fT3 = (const float*)&cT3;
  const float* fP3 = (const float*)&cP3; const float* fR2 = (const float*)&cR2;
  const float* fT2 = (const float*)&cT2; const float* fP2 = (const float*)&cP2;
  const float* fDT = (const float*)&cDT; const float* fDP = (const float*)&cDP;

  float px[EPT], py[EPT], pz[EPT];
  float sx = 0.f, sy = 0.f, sz = 0.f;
  #pragma unroll
  for (int e = 0; e < EPT; ++e) {
    float r3v = fR3[e];
    float th3 = fT3[e] + fDT[e];
    float ph3 = fP3[e] + fDP[e];
    float r2v = fR2[e];
    float th2 = fT2[e];
    float ph2 = fP2[e];
    float st3 = __sinf(th3), ct3 = __cosf(th3);
    float sp3 = __sinf(ph3), cp3 = __cosf(ph3);
    float st2 = __sinf(th2), ct2 = __cosf(th2);
    float sp2 = __sinf(ph2), cp2 = __cosf(ph2);
    sx += r3v * st3 * cp3 - r2v * st2 * cp2; px[e] = sx;
    sy += r3v * st3 * sp3 - r2v * st2 * sp2; py[e] = sy;
    sz += r3v * ct3 - r2v * ct2;             pz[e] = sz;
  }

  float ix = sx, iy = sy, iz = sz;
  #pragma unroll
  for (int off = 1; off < 64; off <<= 1) {
    float ax = __shfl_up(ix, off, 64);
    float ay = __shfl_up(iy, off, 64);
    float az = __shfl_up(iz, off, 64);
    if (lane >= off) { ix += ax; iy += ay; iz += az; }
  }
  const float exs = ix - sx, eys = iy - sy, ezs = iz - sz;

  __shared__ float wtot[3][NWAVES];
  __shared__ float redbuf[NWAVES];
  if (lane == 63) { wtot[0][wave] = ix; wtot[1][wave] = iy; wtot[2][wave] = iz; }
  __syncthreads();

  float wx = 0.f, wy = 0.f, wz = 0.f;
  #pragma unroll
  for (int w = 0; w < NWAVES; ++w) {
    if (w < wave) { wx += wtot[0][w]; wy += wtot[1][w]; wz += wtot[2][w]; }
  }

  const float bx = carx + wx + exs;
  const float by = cary + wy + eys;
  const float bz = carz + wz + ezs;

  float acc = 0.f;
  #pragma unroll
  for (int e = 0; e < EPT; ++e) {
    acc += fabsf(bx + px[e]) + fabsf(by + py[e]) + fabsf(bz + pz[e]);
  }
  if (c == 0 && t == 0) acc += fabsf(ox) + fabsf(oy) + fabsf(oz);

  #pragma unroll
  for (int off = 32; off > 0; off >>= 1) acc += __shfl_down(acc, off, 64);
  if (lane == 0) redbuf[wave] = acc;
  __syncthreads();
  if (t == 0) {
    float s = 0.f;
    #pragma unroll
    for (int w = 0; w < NWAVES; ++w) s += redbuf[w];
    atomicAdd(out, s * (1.0f / (float)(NPTS + 1)));
  }
}

extern "C" void kernel_launch(void* const* d_in, const int* in_sizes, int n_in,
                              void* d_out, int out_size, void* d_ws, size_t ws_size,
                              hipStream_t stream) {
  const float* o3 = (const float*)d_in[0];  // origin_3D      (B,3,1)
  const float* s3 = (const float*)d_in[1];  // spherical_3D   (B,3,N)
  const float* o2 = (const float*)d_in[2];  // origin_2D      (B,3,1)
  const float* s2 = (const float*)d_in[3];  // spherical_2D   (B,3,N)
  const float* df = (const float*)d_in[4];  // deformation    (B,2,N)
  float* out = (float*)d_out;
  char* ws = (char*)d_ws;

  if (ws_size >= WS_NEED) {
    float4* agg     = (float4*)(ws + WS_AGG_OFF);
    float*  partial = (float*)(ws + WS_PARTIAL_OFF);
    float*  dx      = (float*)(ws + WS_DX_OFF);
    float*  dy      = dx + NPOINTS;
    float*  dz      = dy + NPOINTS;
    k1_diff<<<A_NBLK, A_THREADS, 0, stream>>>(s3, s2, df, agg, dx, dy, dz);
    k2_scan<<<A_NBLK, A_THREADS, 0, stream>>>(o3, o2, agg, dx, dy, dz, partial);
    k3_final<<<1, 256, 0, stream>>>(partial, out);
  } else {
    float4* agg = (float4*)ws;              // 64 KB
    hipMemsetAsync(out, 0, sizeof(float) * out_size, stream);
    k_agg<<<NBLK, THREADS, 0, stream>>>(s3, s2, df, agg);
    k_scan<<<NBLK, THREADS, 0, stream>>>(o3, s3, o2, s2, df, agg, out);
  }
}